// Round 3
// baseline (960.331 us; speedup 1.0000x reference)
//
#include <hip/hip_runtime.h>
#include <hip/hip_bf16.h>
#include <math.h>

// TemporalTransformerConv (TGAT-like) for MI355X.
// dims: dim_node=128, dim_edge=64, dim_time=64, dim_out=128, H=2 (head dim 64)
// Round 3: identical math to round 2; output written as FLOAT32 (reference's
// output dtype -> d_out is float*). Rounds 1-2 wrote bf16 -> identical-garbage
// signature (absmax 8.0429 both rounds).
// ws layout (floats): qbias[128] | den[2*ndst] | Q[ndst*128] | agg[ndst*128]

__global__ void k_init(float* agg, float* den, int ndst) {
    int i = blockIdx.x * blockDim.x + threadIdx.x;
    int stride = gridDim.x * blockDim.x;
    int n = ndst * 128;
    for (; i < n; i += stride) {
        agg[i] = 0.f;
        if (i < ndst * 2) den[i] = 0.f;
    }
}

__global__ void k_prep(float* qbias, const float* __restrict__ wq_w,
                       const float* __restrict__ wq_b, const float* __restrict__ time_b) {
    int c = threadIdx.x;
    if (c < 128) {
        float s = wq_b[c];
        for (int j = 0; j < 64; ++j)
            s += cosf(time_b[j]) * wq_w[(128 + j) * 128 + c];
        qbias[c] = s;
    }
}

// Q[ndst,128] = h_dst @ wq_w[0:128,:] + qbias
__global__ __launch_bounds__(256) void k_q(
    float* __restrict__ Q, const float* __restrict__ h,
    const float* __restrict__ wq_w, const float* __restrict__ qbias, int ndst)
{
    __shared__ float As[64 * 128];  // 32 KB
    int row0 = blockIdx.x * 64;
    int tid = threadIdx.x;
    for (int idx = tid; idx < 64 * 128; idx += 256) {
        int r = idx >> 7, c = idx & 127;
        int gr = row0 + r;
        As[idx] = (gr < ndst) ? h[(size_t)gr * 128 + c] : 0.f;
    }
    __syncthreads();
    int cg = tid & 31, rg = tid >> 5;
    int c0 = cg * 4;
    float acc[8][4];
    #pragma unroll
    for (int i = 0; i < 8; ++i) { acc[i][0]=0.f; acc[i][1]=0.f; acc[i][2]=0.f; acc[i][3]=0.f; }
    for (int k = 0; k < 128; k += 4) {
        float4 w0 = *reinterpret_cast<const float4*>(wq_w + (size_t)(k+0)*128 + c0);
        float4 w1 = *reinterpret_cast<const float4*>(wq_w + (size_t)(k+1)*128 + c0);
        float4 w2 = *reinterpret_cast<const float4*>(wq_w + (size_t)(k+2)*128 + c0);
        float4 w3 = *reinterpret_cast<const float4*>(wq_w + (size_t)(k+3)*128 + c0);
        #pragma unroll
        for (int i = 0; i < 8; ++i) {
            float4 a = *reinterpret_cast<const float4*>(&As[(rg*8+i)*128 + k]);
            acc[i][0] = fmaf(a.x,w0.x,fmaf(a.y,w1.x,fmaf(a.z,w2.x,fmaf(a.w,w3.x,acc[i][0]))));
            acc[i][1] = fmaf(a.x,w0.y,fmaf(a.y,w1.y,fmaf(a.z,w2.y,fmaf(a.w,w3.y,acc[i][1]))));
            acc[i][2] = fmaf(a.x,w0.z,fmaf(a.y,w1.z,fmaf(a.z,w2.z,fmaf(a.w,w3.z,acc[i][2]))));
            acc[i][3] = fmaf(a.x,w0.w,fmaf(a.y,w1.w,fmaf(a.z,w2.w,fmaf(a.w,w3.w,acc[i][3]))));
        }
    }
    float q0 = qbias[c0], q1 = qbias[c0+1], q2 = qbias[c0+2], q3 = qbias[c0+3];
    #pragma unroll
    for (int i = 0; i < 8; ++i) {
        int r = row0 + rg*8 + i;
        if (r < ndst) {
            float4 o = make_float4(acc[i][0]+q0, acc[i][1]+q1, acc[i][2]+q2, acc[i][3]+q3);
            *reinterpret_cast<float4*>(Q + (size_t)r*128 + c0) = o;
        }
    }
}

// Fused per-edge pass: K_in=[h_src[nbr], ef, time_feat]; att=leaky(Qh.Kh);
// ex=exp(att) (no max subtraction; exactly equivalent after normalization);
// den[d,h]+=ex; agg[d,:]+=ex*V
__global__ __launch_bounds__(256) void k_kv(
    const float* __restrict__ h, const int* __restrict__ nbr, const int* __restrict__ edst,
    const float* __restrict__ dt, const float* __restrict__ ef,
    const float* __restrict__ time_w, const float* __restrict__ time_b,
    const float* __restrict__ wk_w, const float* __restrict__ wk_b,
    const float* __restrict__ wv_w, const float* __restrict__ wv_b,
    const float* __restrict__ Q, float* __restrict__ den, float* __restrict__ agg,
    int ndst, int E)
{
    __shared__ float As[64 * 256];  // exactly 64 KB, no other LDS
    int e0 = blockIdx.x * 64;
    int tid = threadIdx.x;
    // Each thread owns one K_in column for all 64 edges of the tile.
    {
        int cc = tid;
        if (cc < 128) {
            for (int el = 0; el < 64; ++el) {
                int e = e0 + el;
                float v = 0.f;
                if (e < E) v = h[(size_t)(ndst + nbr[e]) * 128 + cc];
                As[el * 256 + cc] = v;
            }
        } else if (cc < 192) {
            int j = cc - 128;
            for (int el = 0; el < 64; ++el) {
                int e = e0 + el;
                float v = 0.f;
                if (e < E) v = ef[(size_t)e * 64 + j];
                As[el * 256 + cc] = v;
            }
        } else {
            int j = cc - 192;
            float tw = time_w[j], tb = time_b[j];
            for (int el = 0; el < 64; ++el) {
                int e = e0 + el;
                float v = 0.f;
                if (e < E) v = cosf(dt[e] * tw + tb);
                As[el * 256 + cc] = v;
            }
        }
    }
    __syncthreads();

    int cg = tid & 31, rg = tid >> 5;
    int c0 = cg * 4;
    int lane = tid & 63;
    int ehead = cg >> 4;  // head owning this thread's columns (c0<64 -> 0, else 1)

    int  dloc[8];
    bool ev[8];
    #pragma unroll
    for (int i = 0; i < 8; ++i) {
        int e = e0 + rg * 8 + i;
        ev[i] = (e < E);
        dloc[i] = ev[i] ? edst[e] : 0;
    }

    // --- K GEMM ---
    float acc[8][4];
    #pragma unroll
    for (int i = 0; i < 8; ++i) { acc[i][0]=0.f; acc[i][1]=0.f; acc[i][2]=0.f; acc[i][3]=0.f; }
    for (int k = 0; k < 256; k += 4) {
        float4 w0 = *reinterpret_cast<const float4*>(wk_w + (size_t)(k+0)*128 + c0);
        float4 w1 = *reinterpret_cast<const float4*>(wk_w + (size_t)(k+1)*128 + c0);
        float4 w2 = *reinterpret_cast<const float4*>(wk_w + (size_t)(k+2)*128 + c0);
        float4 w3 = *reinterpret_cast<const float4*>(wk_w + (size_t)(k+3)*128 + c0);
        #pragma unroll
        for (int i = 0; i < 8; ++i) {
            float4 a = *reinterpret_cast<const float4*>(&As[(rg*8+i)*256 + k]);
            acc[i][0] = fmaf(a.x,w0.x,fmaf(a.y,w1.x,fmaf(a.z,w2.x,fmaf(a.w,w3.x,acc[i][0]))));
            acc[i][1] = fmaf(a.x,w0.y,fmaf(a.y,w1.y,fmaf(a.z,w2.y,fmaf(a.w,w3.y,acc[i][1]))));
            acc[i][2] = fmaf(a.x,w0.z,fmaf(a.y,w1.z,fmaf(a.z,w2.z,fmaf(a.w,w3.z,acc[i][2]))));
            acc[i][3] = fmaf(a.x,w0.w,fmaf(a.y,w1.w,fmaf(a.z,w2.w,fmaf(a.w,w3.w,acc[i][3]))));
        }
    }
    float kb0 = wk_b[c0], kb1 = wk_b[c0+1], kb2 = wk_b[c0+2], kb3 = wk_b[c0+3];
    float p[8];
    #pragma unroll
    for (int i = 0; i < 8; ++i) {
        float4 q = *reinterpret_cast<const float4*>(Q + (size_t)dloc[i] * 128 + c0);
        p[i] = (acc[i][0]+kb0)*q.x + (acc[i][1]+kb1)*q.y + (acc[i][2]+kb2)*q.z + (acc[i][3]+kb3)*q.w;
    }
    // reduce over the 16 lanes holding one (row, head): bits 0..3 of lane
    #pragma unroll
    for (int m = 1; m <= 8; m <<= 1) {
        #pragma unroll
        for (int i = 0; i < 8; ++i) p[i] += __shfl_xor(p[i], m, 64);
    }
    float ex[8];
    #pragma unroll
    for (int i = 0; i < 8; ++i) {
        float ar = p[i];
        ar = (ar >= 0.f) ? ar : 0.2f * ar;   // leaky_relu(.,0.2)
        ex[i] = expf(ar);                     // no max subtraction (|ar| bounded)
    }
    if ((lane & 15) == 0) {
        #pragma unroll
        for (int i = 0; i < 8; ++i)
            if (ev[i]) atomicAdd(&den[(size_t)dloc[i] * 2 + ehead], ex[i]);
    }

    // --- V GEMM ---
    #pragma unroll
    for (int i = 0; i < 8; ++i) { acc[i][0]=0.f; acc[i][1]=0.f; acc[i][2]=0.f; acc[i][3]=0.f; }
    for (int k = 0; k < 256; k += 4) {
        float4 w0 = *reinterpret_cast<const float4*>(wv_w + (size_t)(k+0)*128 + c0);
        float4 w1 = *reinterpret_cast<const float4*>(wv_w + (size_t)(k+1)*128 + c0);
        float4 w2 = *reinterpret_cast<const float4*>(wv_w + (size_t)(k+2)*128 + c0);
        float4 w3 = *reinterpret_cast<const float4*>(wv_w + (size_t)(k+3)*128 + c0);
        #pragma unroll
        for (int i = 0; i < 8; ++i) {
            float4 a = *reinterpret_cast<const float4*>(&As[(rg*8+i)*256 + k]);
            acc[i][0] = fmaf(a.x,w0.x,fmaf(a.y,w1.x,fmaf(a.z,w2.x,fmaf(a.w,w3.x,acc[i][0]))));
            acc[i][1] = fmaf(a.x,w0.y,fmaf(a.y,w1.y,fmaf(a.z,w2.y,fmaf(a.w,w3.y,acc[i][1]))));
            acc[i][2] = fmaf(a.x,w0.z,fmaf(a.y,w1.z,fmaf(a.z,w2.z,fmaf(a.w,w3.z,acc[i][2]))));
            acc[i][3] = fmaf(a.x,w0.w,fmaf(a.y,w1.w,fmaf(a.z,w2.w,fmaf(a.w,w3.w,acc[i][3]))));
        }
    }
    float vb0 = wv_b[c0], vb1 = wv_b[c0+1], vb2 = wv_b[c0+2], vb3 = wv_b[c0+3];
    #pragma unroll
    for (int i = 0; i < 8; ++i) {
        if (ev[i]) {
            float s = ex[i];  // this thread's ex is for the head its columns belong to
            float* dst = agg + (size_t)dloc[i] * 128 + c0;
            atomicAdd(dst + 0, s * (acc[i][0] + vb0));
            atomicAdd(dst + 1, s * (acc[i][1] + vb1));
            atomicAdd(dst + 2, s * (acc[i][2] + vb2));
            atomicAdd(dst + 3, s * (acc[i][3] + vb3));
        }
    }
}

// out = LN(relu([agg/den, h_dst] @ wo + wo_b)) * g + b   (f32 out)
__global__ __launch_bounds__(256) void k_out(
    const float* __restrict__ agg, const float* __restrict__ den,
    const float* __restrict__ h, const float* __restrict__ wo_w, const float* __restrict__ wo_b,
    const float* __restrict__ ln_g, const float* __restrict__ ln_b,
    float* __restrict__ out, int ndst)
{
    __shared__ float As[64 * 256];  // exactly 64 KB
    int row0 = blockIdx.x * 64;
    int tid = threadIdx.x;
    for (int idx = tid; idx < 64 * 256; idx += 256) {
        int r = idx >> 8, c = idx & 255;
        int gr = row0 + r;
        float v = 0.f;
        if (gr < ndst) {
            if (c < 128) {
                float dd = den[(size_t)gr * 2 + (c >> 6)];
                v = (dd > 0.f) ? agg[(size_t)gr * 128 + c] / dd : 0.f;
            } else {
                v = h[(size_t)gr * 128 + (c - 128)];
            }
        }
        As[idx] = v;
    }
    __syncthreads();
    int cg = tid & 31, rg = tid >> 5;
    int c0 = cg * 4;
    float acc[8][4];
    #pragma unroll
    for (int i = 0; i < 8; ++i) { acc[i][0]=0.f; acc[i][1]=0.f; acc[i][2]=0.f; acc[i][3]=0.f; }
    for (int k = 0; k < 256; k += 4) {
        float4 w0 = *reinterpret_cast<const float4*>(wo_w + (size_t)(k+0)*128 + c0);
        float4 w1 = *reinterpret_cast<const float4*>(wo_w + (size_t)(k+1)*128 + c0);
        float4 w2 = *reinterpret_cast<const float4*>(wo_w + (size_t)(k+2)*128 + c0);
        float4 w3 = *reinterpret_cast<const float4*>(wo_w + (size_t)(k+3)*128 + c0);
        #pragma unroll
        for (int i = 0; i < 8; ++i) {
            float4 a = *reinterpret_cast<const float4*>(&As[(rg*8+i)*256 + k]);
            acc[i][0] = fmaf(a.x,w0.x,fmaf(a.y,w1.x,fmaf(a.z,w2.x,fmaf(a.w,w3.x,acc[i][0]))));
            acc[i][1] = fmaf(a.x,w0.y,fmaf(a.y,w1.y,fmaf(a.z,w2.y,fmaf(a.w,w3.y,acc[i][1]))));
            acc[i][2] = fmaf(a.x,w0.z,fmaf(a.y,w1.z,fmaf(a.z,w2.z,fmaf(a.w,w3.z,acc[i][2]))));
            acc[i][3] = fmaf(a.x,w0.w,fmaf(a.y,w1.w,fmaf(a.z,w2.w,fmaf(a.w,w3.w,acc[i][3]))));
        }
    }
    float b0 = wo_b[c0], b1 = wo_b[c0+1], b2 = wo_b[c0+2], b3 = wo_b[c0+3];
    float g0 = ln_g[c0], g1 = ln_g[c0+1], g2 = ln_g[c0+2], g3 = ln_g[c0+3];
    float l0 = ln_b[c0], l1 = ln_b[c0+1], l2 = ln_b[c0+2], l3 = ln_b[c0+3];
    #pragma unroll
    for (int i = 0; i < 8; ++i) {
        float x0 = fmaxf(acc[i][0] + b0, 0.f);
        float x1 = fmaxf(acc[i][1] + b1, 0.f);
        float x2 = fmaxf(acc[i][2] + b2, 0.f);
        float x3 = fmaxf(acc[i][3] + b3, 0.f);
        float s1 = x0 + x1 + x2 + x3;
        float s2 = x0*x0 + x1*x1 + x2*x2 + x3*x3;
        #pragma unroll
        for (int mm = 1; mm <= 16; mm <<= 1) {
            s1 += __shfl_xor(s1, mm, 64);
            s2 += __shfl_xor(s2, mm, 64);
        }
        float mean = s1 * (1.f / 128.f);
        float var  = s2 * (1.f / 128.f) - mean * mean;
        float rstd = rsqrtf(var + 1e-5f);
        int r = row0 + rg * 8 + i;
        if (r < ndst) {
            float4 o = make_float4((x0 - mean) * rstd * g0 + l0,
                                   (x1 - mean) * rstd * g1 + l1,
                                   (x2 - mean) * rstd * g2 + l2,
                                   (x3 - mean) * rstd * g3 + l3);
            *reinterpret_cast<float4*>(out + (size_t)r * 128 + c0) = o;
        }
    }
}

extern "C" void kernel_launch(void* const* d_in, const int* in_sizes, int n_in,
                              void* d_out, int out_size, void* d_ws, size_t ws_size,
                              hipStream_t stream) {
    const float* h      = (const float*)d_in[0];
    const float* dt     = (const float*)d_in[1];
    const float* ef     = (const float*)d_in[2];
    const float* time_w = (const float*)d_in[3];
    const float* time_b = (const float*)d_in[4];
    const float* wq_w   = (const float*)d_in[5];
    const float* wq_b   = (const float*)d_in[6];
    const float* wk_w   = (const float*)d_in[7];
    const float* wk_b   = (const float*)d_in[8];
    const float* wv_w   = (const float*)d_in[9];
    const float* wv_b   = (const float*)d_in[10];
    const float* wo_w   = (const float*)d_in[11];
    const float* wo_b   = (const float*)d_in[12];
    const float* ln_g   = (const float*)d_in[13];
    const float* ln_b   = (const float*)d_in[14];
    const int* nbr      = (const int*)d_in[15];
    const int* edst     = (const int*)d_in[16];

    int E    = in_sizes[1];
    int ndst = out_size / 128;

    float* ws    = (float*)d_ws;
    float* qbias = ws;                          // 128
    float* den   = qbias + 128;                 // 2*ndst
    float* Q     = den + (size_t)ndst * 2;      // ndst*128
    float* agg   = Q + (size_t)ndst * 128;      // ndst*128
    // total: (128 + 2*ndst + 2*ndst*128) * 4 B  = 51.6 MB for ndst=50000

    k_init<<<2048, 256, 0, stream>>>(agg, den, ndst);
    k_prep<<<1, 128, 0, stream>>>(qbias, wq_w, wq_b, time_b);
    k_q<<<(ndst + 63) / 64, 256, 0, stream>>>(Q, h, wq_w, qbias, ndst);
    k_kv<<<(E + 63) / 64, 256, 0, stream>>>(h, nbr, edst, dt, ef, time_w, time_b,
                                            wk_w, wk_b, wv_w, wv_b, Q, den, agg, ndst, E);
    k_out<<<(ndst + 63) / 64, 256, 0, stream>>>(agg, den, h, wo_w, wo_b, ln_g, ln_b,
                                                (float*)d_out, ndst);
}

// Round 4
// 559.333 us; speedup vs baseline: 1.7169x; 1.7169x over previous
//
#include <hip/hip_runtime.h>
#include <hip/hip_bf16.h>
#include <math.h>

// TemporalTransformerConv (TGAT-like) for MI355X — round 4.
// k_kv rewritten: bf16 MFMA (16x16x32) for K and V edge GEMMs, 32 KB swizzled
// bf16 LDS A-tile, f32 Q-gather for the att dot, atomics for segment softmax.
// ws (floats): qbias[128] | den[2n] | Q[n*128] | agg[n*128] | wkT,wvT (bf16 [128][256])

using bf16 = __hip_bfloat16;
typedef __attribute__((ext_vector_type(8))) short short8;
typedef __attribute__((ext_vector_type(4))) float f32x4;

static __device__ __forceinline__ unsigned short bf16_bits(float x) {
    bf16 h = __float2bfloat16(x);
    unsigned short b;
    __builtin_memcpy(&b, &h, 2);
    return b;
}

__global__ void k_init(float* agg, float* den, int ndst) {
    int i = blockIdx.x * blockDim.x + threadIdx.x;
    int stride = gridDim.x * blockDim.x;
    int n = ndst * 128;
    for (; i < n; i += stride) {
        agg[i] = 0.f;
        if (i < ndst * 2) den[i] = 0.f;
    }
}

__global__ void k_prep(float* qbias, const float* __restrict__ wq_w,
                       const float* __restrict__ wq_b, const float* __restrict__ time_b) {
    int c = threadIdx.x;
    if (c < 128) {
        float s = wq_b[c];
        for (int j = 0; j < 64; ++j)
            s += cosf(time_b[j]) * wq_w[(128 + j) * 128 + c];
        qbias[c] = s;
    }
}

// pack wk_w/wv_w (256x128 f32, k-major) -> bf16 transposed [n][k] (128x256)
__global__ void k_pack(unsigned short* wkT, unsigned short* wvT,
                       const float* __restrict__ wk_w, const float* __restrict__ wv_w) {
    int idx = blockIdx.x * blockDim.x + threadIdx.x;  // 128*256 = 32768
    if (idx < 32768) {
        int n = idx >> 8, k = idx & 255;
        wkT[idx] = bf16_bits(wk_w[(size_t)k * 128 + n]);
        wvT[idx] = bf16_bits(wv_w[(size_t)k * 128 + n]);
    }
}

// Q[ndst,128] = h_dst @ wq_w[0:128,:] + qbias   (f32)
__global__ __launch_bounds__(256) void k_q(
    float* __restrict__ Q, const float* __restrict__ h,
    const float* __restrict__ wq_w, const float* __restrict__ qbias, int ndst)
{
    __shared__ float As[64 * 128];  // 32 KB
    int row0 = blockIdx.x * 64;
    int tid = threadIdx.x;
    for (int idx = tid; idx < 64 * 128; idx += 256) {
        int r = idx >> 7, c = idx & 127;
        int gr = row0 + r;
        As[idx] = (gr < ndst) ? h[(size_t)gr * 128 + c] : 0.f;
    }
    __syncthreads();
    int cg = tid & 31, rg = tid >> 5;
    int c0 = cg * 4;
    float acc[8][4];
    #pragma unroll
    for (int i = 0; i < 8; ++i) { acc[i][0]=0.f; acc[i][1]=0.f; acc[i][2]=0.f; acc[i][3]=0.f; }
    for (int k = 0; k < 128; k += 4) {
        float4 w0 = *reinterpret_cast<const float4*>(wq_w + (size_t)(k+0)*128 + c0);
        float4 w1 = *reinterpret_cast<const float4*>(wq_w + (size_t)(k+1)*128 + c0);
        float4 w2 = *reinterpret_cast<const float4*>(wq_w + (size_t)(k+2)*128 + c0);
        float4 w3 = *reinterpret_cast<const float4*>(wq_w + (size_t)(k+3)*128 + c0);
        #pragma unroll
        for (int i = 0; i < 8; ++i) {
            float4 a = *reinterpret_cast<const float4*>(&As[(rg*8+i)*128 + k]);
            acc[i][0] = fmaf(a.x,w0.x,fmaf(a.y,w1.x,fmaf(a.z,w2.x,fmaf(a.w,w3.x,acc[i][0]))));
            acc[i][1] = fmaf(a.x,w0.y,fmaf(a.y,w1.y,fmaf(a.z,w2.y,fmaf(a.w,w3.y,acc[i][1]))));
            acc[i][2] = fmaf(a.x,w0.z,fmaf(a.y,w1.z,fmaf(a.z,w2.z,fmaf(a.w,w3.z,acc[i][2]))));
            acc[i][3] = fmaf(a.x,w0.w,fmaf(a.y,w1.w,fmaf(a.z,w2.w,fmaf(a.w,w3.w,acc[i][3]))));
        }
    }
    float q0 = qbias[c0], q1 = qbias[c0+1], q2 = qbias[c0+2], q3 = qbias[c0+3];
    #pragma unroll
    for (int i = 0; i < 8; ++i) {
        int r = row0 + rg*8 + i;
        if (r < ndst) {
            float4 o = make_float4(acc[i][0]+q0, acc[i][1]+q1, acc[i][2]+q2, acc[i][3]+q3);
            *reinterpret_cast<float4*>(Q + (size_t)r*128 + c0) = o;
        }
    }
}

// Fused edge pass with MFMA. 64 edges/block, 4 waves = (2 edge-halves)x(2 heads).
__global__ __launch_bounds__(256) void k_kv(
    const float* __restrict__ h, const int* __restrict__ nbr, const int* __restrict__ edst,
    const float* __restrict__ dt, const float* __restrict__ ef,
    const float* __restrict__ time_w, const float* __restrict__ time_b,
    const unsigned short* __restrict__ wkT, const unsigned short* __restrict__ wvT,
    const float* __restrict__ wk_b, const float* __restrict__ wv_b,
    const float* __restrict__ Q, float* __restrict__ den, float* __restrict__ agg,
    int ndst, int E)
{
    __shared__ unsigned short As[64 * 256];  // 32 KB, swizzled: us_idx = el*256 + (c ^ ((el&7)<<3))
    __shared__ int dstl[64];
    int e0 = blockIdx.x * 64;
    int tid = threadIdx.x;

    if (tid < 64) {
        int e = e0 + tid;
        dstl[tid] = (e < E) ? edst[e] : 0;
    }

    // ---- staging: thread handles column-pair p for 32 edges ----
    {
        int p = tid & 127;            // column pair index (cols 2p, 2p+1)
        int elbase = (tid >> 7) * 32; // edges [elbase, elbase+32)
        unsigned* As32 = reinterpret_cast<unsigned*>(As);
        if (p < 64) {
            int c = p * 2;
            for (int it = 0; it < 32; ++it) {
                int el = elbase + it;
                int e = e0 + el;
                float2 v = make_float2(0.f, 0.f);
                if (e < E) v = *reinterpret_cast<const float2*>(
                        &h[(size_t)(ndst + nbr[e]) * 128 + c]);
                unsigned pk = (unsigned)bf16_bits(v.x) | ((unsigned)bf16_bits(v.y) << 16);
                As32[el * 128 + (p ^ ((el & 7) << 2))] = pk;
            }
        } else if (p < 96) {
            int c = (p - 64) * 2;
            for (int it = 0; it < 32; ++it) {
                int el = elbase + it;
                int e = e0 + el;
                float2 v = make_float2(0.f, 0.f);
                if (e < E) v = *reinterpret_cast<const float2*>(&ef[(size_t)e * 64 + c]);
                unsigned pk = (unsigned)bf16_bits(v.x) | ((unsigned)bf16_bits(v.y) << 16);
                As32[el * 128 + (p ^ ((el & 7) << 2))] = pk;
            }
        } else {
            int j2 = (p - 96) * 2;
            float tw0 = time_w[j2], tw1 = time_w[j2 + 1];
            float tb0 = time_b[j2], tb1 = time_b[j2 + 1];
            for (int it = 0; it < 32; ++it) {
                int el = elbase + it;
                int e = e0 + el;
                float d = (e < E) ? dt[e] : 0.f;
                float v0 = __cosf(fmaf(d, tw0, tb0));
                float v1 = __cosf(fmaf(d, tw1, tb1));
                unsigned pk = (unsigned)bf16_bits(v0) | ((unsigned)bf16_bits(v1) << 16);
                As32[el * 128 + (p ^ ((el & 7) << 2))] = pk;
            }
        }
    }
    __syncthreads();

    int lane = tid & 63;
    int l15 = lane & 15;          // A row within tile / D col within tile
    int lk  = lane >> 4;          // A k-chunk / D row-group
    int nw  = (tid >> 6) & 1;     // head (column half)
    int mw  = tid >> 7;           // edge half
    int rowbase = mw * 32;

    // destination rows + validity for this lane's D rows
    int   dstr[2][4];
    bool  evv[2][4];
    #pragma unroll
    for (int mt = 0; mt < 2; ++mt)
        #pragma unroll
        for (int j = 0; j < 4; ++j) {
            int rl = rowbase + mt * 16 + lk * 4 + j;
            dstr[mt][j] = dstl[rl];
            evv[mt][j]  = (e0 + rl) < E;
        }

    // Q gather (f32): qg[mt][nt][j] = Q[dst, nw*64 + nt*16 + l15]
    float qg[2][4][4];
    #pragma unroll
    for (int mt = 0; mt < 2; ++mt)
        #pragma unroll
        for (int nt = 0; nt < 4; ++nt) {
            int gc = nw * 64 + nt * 16 + l15;
            #pragma unroll
            for (int j = 0; j < 4; ++j)
                qg[mt][nt][j] = Q[(size_t)dstr[mt][j] * 128 + gc];
        }

    // A fragments (shared by K and V GEMMs): a[mt][kk]
    short8 a[2][8];
    #pragma unroll
    for (int mt = 0; mt < 2; ++mt) {
        int row = rowbase + mt * 16 + l15;
        int sw  = (row & 7) << 3;
        #pragma unroll
        for (int kk = 0; kk < 8; ++kk) {
            int coff = (kk * 32 + lk * 8) ^ sw;
            a[mt][kk] = *reinterpret_cast<const short8*>(&As[row * 256 + coff]);
        }
    }

    // ---- K GEMM ----
    f32x4 ck[2][4];
    #pragma unroll
    for (int mt = 0; mt < 2; ++mt)
        #pragma unroll
        for (int nt = 0; nt < 4; ++nt) ck[mt][nt] = (f32x4){0.f, 0.f, 0.f, 0.f};
    #pragma unroll
    for (int nt = 0; nt < 4; ++nt) {
        const unsigned short* bp = wkT + (size_t)(nw * 64 + nt * 16 + l15) * 256 + lk * 8;
        #pragma unroll
        for (int kk = 0; kk < 8; ++kk) {
            short8 b = *reinterpret_cast<const short8*>(bp + kk * 32);
            ck[0][nt] = __builtin_amdgcn_mfma_f32_16x16x32_bf16(a[0][kk], b, ck[0][nt], 0, 0, 0);
            ck[1][nt] = __builtin_amdgcn_mfma_f32_16x16x32_bf16(a[1][kk], b, ck[1][nt], 0, 0, 0);
        }
    }

    // ---- att = leaky_relu(sum_c (K+kb)*Qg), reduce over l15 lanes ----
    float p[2][4];
    #pragma unroll
    for (int mt = 0; mt < 2; ++mt)
        #pragma unroll
        for (int j = 0; j < 4; ++j) p[mt][j] = 0.f;
    #pragma unroll
    for (int nt = 0; nt < 4; ++nt) {
        float kb = wk_b[nw * 64 + nt * 16 + l15];
        #pragma unroll
        for (int mt = 0; mt < 2; ++mt)
            #pragma unroll
            for (int j = 0; j < 4; ++j)
                p[mt][j] += (ck[mt][nt][j] + kb) * qg[mt][nt][j];
    }
    #pragma unroll
    for (int m = 1; m <= 8; m <<= 1) {
        #pragma unroll
        for (int mt = 0; mt < 2; ++mt)
            #pragma unroll
            for (int j = 0; j < 4; ++j)
                p[mt][j] += __shfl_xor(p[mt][j], m, 64);
    }
    float ex[2][4];
    #pragma unroll
    for (int mt = 0; mt < 2; ++mt)
        #pragma unroll
        for (int j = 0; j < 4; ++j) {
            float ar = p[mt][j];
            ar = (ar >= 0.f) ? ar : 0.2f * ar;
            ex[mt][j] = __expf(ar);
        }
    if (l15 == 0) {
        #pragma unroll
        for (int mt = 0; mt < 2; ++mt)
            #pragma unroll
            for (int j = 0; j < 4; ++j)
                if (evv[mt][j]) atomicAdd(&den[(size_t)dstr[mt][j] * 2 + nw], ex[mt][j]);
    }

    // ---- V GEMM ----
    f32x4 cv[2][4];
    #pragma unroll
    for (int mt = 0; mt < 2; ++mt)
        #pragma unroll
        for (int nt = 0; nt < 4; ++nt) cv[mt][nt] = (f32x4){0.f, 0.f, 0.f, 0.f};
    #pragma unroll
    for (int nt = 0; nt < 4; ++nt) {
        const unsigned short* bp = wvT + (size_t)(nw * 64 + nt * 16 + l15) * 256 + lk * 8;
        #pragma unroll
        for (int kk = 0; kk < 8; ++kk) {
            short8 b = *reinterpret_cast<const short8*>(bp + kk * 32);
            cv[0][nt] = __builtin_amdgcn_mfma_f32_16x16x32_bf16(a[0][kk], b, cv[0][nt], 0, 0, 0);
            cv[1][nt] = __builtin_amdgcn_mfma_f32_16x16x32_bf16(a[1][kk], b, cv[1][nt], 0, 0, 0);
        }
    }
    // ---- weighted scatter: agg[dst, c] += ex * (V + vb) ----
    #pragma unroll
    for (int nt = 0; nt < 4; ++nt) {
        int gc = nw * 64 + nt * 16 + l15;
        float vb = wv_b[gc];
        #pragma unroll
        for (int mt = 0; mt < 2; ++mt)
            #pragma unroll
            for (int j = 0; j < 4; ++j)
                if (evv[mt][j]) {
                    float vv = (cv[mt][nt][j] + vb) * ex[mt][j];
                    atomicAdd(&agg[(size_t)dstr[mt][j] * 128 + gc], vv);
                }
    }
}

// out = LN(relu([agg/den, h_dst] @ wo + wo_b)) * g + b   (f32 out)
__global__ __launch_bounds__(256) void k_out(
    const float* __restrict__ agg, const float* __restrict__ den,
    const float* __restrict__ h, const float* __restrict__ wo_w, const float* __restrict__ wo_b,
    const float* __restrict__ ln_g, const float* __restrict__ ln_b,
    float* __restrict__ out, int ndst)
{
    __shared__ float As[64 * 256];  // 64 KB
    int row0 = blockIdx.x * 64;
    int tid = threadIdx.x;
    for (int idx = tid; idx < 64 * 256; idx += 256) {
        int r = idx >> 8, c = idx & 255;
        int gr = row0 + r;
        float v = 0.f;
        if (gr < ndst) {
            if (c < 128) {
                float dd = den[(size_t)gr * 2 + (c >> 6)];
                v = (dd > 0.f) ? agg[(size_t)gr * 128 + c] / dd : 0.f;
            } else {
                v = h[(size_t)gr * 128 + (c - 128)];
            }
        }
        As[idx] = v;
    }
    __syncthreads();
    int cg = tid & 31, rg = tid >> 5;
    int c0 = cg * 4;
    float acc[8][4];
    #pragma unroll
    for (int i = 0; i < 8; ++i) { acc[i][0]=0.f; acc[i][1]=0.f; acc[i][2]=0.f; acc[i][3]=0.f; }
    for (int k = 0; k < 256; k += 4) {
        float4 w0 = *reinterpret_cast<const float4*>(wo_w + (size_t)(k+0)*128 + c0);
        float4 w1 = *reinterpret_cast<const float4*>(wo_w + (size_t)(k+1)*128 + c0);
        float4 w2 = *reinterpret_cast<const float4*>(wo_w + (size_t)(k+2)*128 + c0);
        float4 w3 = *reinterpret_cast<const float4*>(wo_w + (size_t)(k+3)*128 + c0);
        #pragma unroll
        for (int i = 0; i < 8; ++i) {
            float4 a = *reinterpret_cast<const float4*>(&As[(rg*8+i)*256 + k]);
            acc[i][0] = fmaf(a.x,w0.x,fmaf(a.y,w1.x,fmaf(a.z,w2.x,fmaf(a.w,w3.x,acc[i][0]))));
            acc[i][1] = fmaf(a.x,w0.y,fmaf(a.y,w1.y,fmaf(a.z,w2.y,fmaf(a.w,w3.y,acc[i][1]))));
            acc[i][2] = fmaf(a.x,w0.z,fmaf(a.y,w1.z,fmaf(a.z,w2.z,fmaf(a.w,w3.z,acc[i][2]))));
            acc[i][3] = fmaf(a.x,w0.w,fmaf(a.y,w1.w,fmaf(a.z,w2.w,fmaf(a.w,w3.w,acc[i][3]))));
        }
    }
    float b0 = wo_b[c0], b1 = wo_b[c0+1], b2 = wo_b[c0+2], b3 = wo_b[c0+3];
    float g0 = ln_g[c0], g1 = ln_g[c0+1], g2 = ln_g[c0+2], g3 = ln_g[c0+3];
    float l0 = ln_b[c0], l1 = ln_b[c0+1], l2 = ln_b[c0+2], l3 = ln_b[c0+3];
    #pragma unroll
    for (int i = 0; i < 8; ++i) {
        float x0 = fmaxf(acc[i][0] + b0, 0.f);
        float x1 = fmaxf(acc[i][1] + b1, 0.f);
        float x2 = fmaxf(acc[i][2] + b2, 0.f);
        float x3 = fmaxf(acc[i][3] + b3, 0.f);
        float s1 = x0 + x1 + x2 + x3;
        float s2 = x0*x0 + x1*x1 + x2*x2 + x3*x3;
        #pragma unroll
        for (int mm = 1; mm <= 16; mm <<= 1) {
            s1 += __shfl_xor(s1, mm, 64);
            s2 += __shfl_xor(s2, mm, 64);
        }
        float mean = s1 * (1.f / 128.f);
        float var  = s2 * (1.f / 128.f) - mean * mean;
        float rstd = rsqrtf(var + 1e-5f);
        int r = row0 + rg * 8 + i;
        if (r < ndst) {
            float4 o = make_float4((x0 - mean) * rstd * g0 + l0,
                                   (x1 - mean) * rstd * g1 + l1,
                                   (x2 - mean) * rstd * g2 + l2,
                                   (x3 - mean) * rstd * g3 + l3);
            *reinterpret_cast<float4*>(out + (size_t)r * 128 + c0) = o;
        }
    }
}

extern "C" void kernel_launch(void* const* d_in, const int* in_sizes, int n_in,
                              void* d_out, int out_size, void* d_ws, size_t ws_size,
                              hipStream_t stream) {
    const float* h      = (const float*)d_in[0];
    const float* dt     = (const float*)d_in[1];
    const float* ef     = (const float*)d_in[2];
    const float* time_w = (const float*)d_in[3];
    const float* time_b = (const float*)d_in[4];
    const float* wq_w   = (const float*)d_in[5];
    const float* wq_b   = (const float*)d_in[6];
    const float* wk_w   = (const float*)d_in[7];
    const float* wk_b   = (const float*)d_in[8];
    const float* wv_w   = (const float*)d_in[9];
    const float* wv_b   = (const float*)d_in[10];
    const float* wo_w   = (const float*)d_in[11];
    const float* wo_b   = (const float*)d_in[12];
    const float* ln_g   = (const float*)d_in[13];
    const float* ln_b   = (const float*)d_in[14];
    const int* nbr      = (const int*)d_in[15];
    const int* edst     = (const int*)d_in[16];

    int E    = in_sizes[1];
    int ndst = out_size / 128;

    float* ws    = (float*)d_ws;
    float* qbias = ws;                          // 128
    float* den   = qbias + 128;                 // 2*ndst
    float* Q     = den + (size_t)ndst * 2;      // ndst*128
    float* agg   = Q + (size_t)ndst * 128;      // ndst*128
    unsigned short* wkT = (unsigned short*)(agg + (size_t)ndst * 128);  // 128*256 bf16
    unsigned short* wvT = wkT + 128 * 256;
    // total ~51.7 MB

    k_init<<<2048, 256, 0, stream>>>(agg, den, ndst);
    k_prep<<<1, 128, 0, stream>>>(qbias, wq_w, wq_b, time_b);
    k_pack<<<128, 256, 0, stream>>>(wkT, wvT, wk_w, wv_w);
    k_q<<<(ndst + 63) / 64, 256, 0, stream>>>(Q, h, wq_w, qbias, ndst);
    k_kv<<<(E + 63) / 64, 256, 0, stream>>>(h, nbr, edst, dt, ef, time_w, time_b,
                                            wkT, wvT, wk_b, wv_b, Q, den, agg, ndst, E);
    k_out<<<(ndst + 63) / 64, 256, 0, stream>>>(agg, den, h, wo_w, wo_b, ln_g, ln_b,
                                                (float*)d_out, ndst);
}

// Round 5
// 548.640 us; speedup vs baseline: 1.7504x; 1.0195x over previous
//
#include <hip/hip_runtime.h>
#include <hip/hip_bf16.h>
#include <math.h>

// TemporalTransformerConv (TGAT-like) for MI355X — round 5.
// k_kv: LDS-free. Each wave owns 16 edges; A-fragments (bf16) built by direct
// per-lane float4 gathers from h/ef (+cos for time slice); K and V GEMMs via
// mfma_f32_16x16x32_bf16 against pre-packed [n][k] bf16 weights; f32 Q-gather
// for the att dot; atomic den/agg scatter. No barrier, no LDS.
// ws (floats): qbias[128] | den[2n] | Q[n*128] | agg[n*128] | wkT,wvT (bf16 [128][256])

using bf16 = __hip_bfloat16;
typedef __attribute__((ext_vector_type(8))) short short8;
typedef __attribute__((ext_vector_type(4))) float f32x4;

static __device__ __forceinline__ unsigned short bf16_bits(float x) {
    bf16 h = __float2bfloat16(x);
    unsigned short b;
    __builtin_memcpy(&b, &h, 2);
    return b;
}
static __device__ __forceinline__ unsigned pk2(float x, float y) {
    return (unsigned)bf16_bits(x) | ((unsigned)bf16_bits(y) << 16);
}

union frag_u { short8 s; unsigned u[4]; };

__global__ void k_init(float* agg, float* den, int ndst) {
    int i = blockIdx.x * blockDim.x + threadIdx.x;
    int stride = gridDim.x * blockDim.x;
    int n = ndst * 128;
    for (; i < n; i += stride) {
        agg[i] = 0.f;
        if (i < ndst * 2) den[i] = 0.f;
    }
}

__global__ void k_prep(float* qbias, const float* __restrict__ wq_w,
                       const float* __restrict__ wq_b, const float* __restrict__ time_b) {
    int c = threadIdx.x;
    if (c < 128) {
        float s = wq_b[c];
        for (int j = 0; j < 64; ++j)
            s += cosf(time_b[j]) * wq_w[(128 + j) * 128 + c];
        qbias[c] = s;
    }
}

// pack wk_w/wv_w (256x128 f32, k-major) -> bf16 transposed [n][k] (128x256)
__global__ void k_pack(unsigned short* wkT, unsigned short* wvT,
                       const float* __restrict__ wk_w, const float* __restrict__ wv_w) {
    int idx = blockIdx.x * blockDim.x + threadIdx.x;  // 128*256 = 32768
    if (idx < 32768) {
        int n = idx >> 8, k = idx & 255;
        wkT[idx] = bf16_bits(wk_w[(size_t)k * 128 + n]);
        wvT[idx] = bf16_bits(wv_w[(size_t)k * 128 + n]);
    }
}

// Q[ndst,128] = h_dst @ wq_w[0:128,:] + qbias   (f32)
__global__ __launch_bounds__(256) void k_q(
    float* __restrict__ Q, const float* __restrict__ h,
    const float* __restrict__ wq_w, const float* __restrict__ qbias, int ndst)
{
    __shared__ float As[64 * 128];  // 32 KB
    int row0 = blockIdx.x * 64;
    int tid = threadIdx.x;
    for (int idx = tid; idx < 64 * 128; idx += 256) {
        int r = idx >> 7, c = idx & 127;
        int gr = row0 + r;
        As[idx] = (gr < ndst) ? h[(size_t)gr * 128 + c] : 0.f;
    }
    __syncthreads();
    int cg = tid & 31, rg = tid >> 5;
    int c0 = cg * 4;
    float acc[8][4];
    #pragma unroll
    for (int i = 0; i < 8; ++i) { acc[i][0]=0.f; acc[i][1]=0.f; acc[i][2]=0.f; acc[i][3]=0.f; }
    for (int k = 0; k < 128; k += 4) {
        float4 w0 = *reinterpret_cast<const float4*>(wq_w + (size_t)(k+0)*128 + c0);
        float4 w1 = *reinterpret_cast<const float4*>(wq_w + (size_t)(k+1)*128 + c0);
        float4 w2 = *reinterpret_cast<const float4*>(wq_w + (size_t)(k+2)*128 + c0);
        float4 w3 = *reinterpret_cast<const float4*>(wq_w + (size_t)(k+3)*128 + c0);
        #pragma unroll
        for (int i = 0; i < 8; ++i) {
            float4 a = *reinterpret_cast<const float4*>(&As[(rg*8+i)*128 + k]);
            acc[i][0] = fmaf(a.x,w0.x,fmaf(a.y,w1.x,fmaf(a.z,w2.x,fmaf(a.w,w3.x,acc[i][0]))));
            acc[i][1] = fmaf(a.x,w0.y,fmaf(a.y,w1.y,fmaf(a.z,w2.y,fmaf(a.w,w3.y,acc[i][1]))));
            acc[i][2] = fmaf(a.x,w0.z,fmaf(a.y,w1.z,fmaf(a.z,w2.z,fmaf(a.w,w3.z,acc[i][2]))));
            acc[i][3] = fmaf(a.x,w0.w,fmaf(a.y,w1.w,fmaf(a.z,w2.w,fmaf(a.w,w3.w,acc[i][3]))));
        }
    }
    float q0 = qbias[c0], q1 = qbias[c0+1], q2 = qbias[c0+2], q3 = qbias[c0+3];
    #pragma unroll
    for (int i = 0; i < 8; ++i) {
        int r = row0 + rg*8 + i;
        if (r < ndst) {
            float4 o = make_float4(acc[i][0]+q0, acc[i][1]+q1, acc[i][2]+q2, acc[i][3]+q3);
            *reinterpret_cast<float4*>(Q + (size_t)r*128 + c0) = o;
        }
    }
}

// Fused edge pass, LDS-free. Wave w handles edges [bid*64 + w*16, +16).
__global__ __launch_bounds__(256) void k_kv(
    const float* __restrict__ h, const int* __restrict__ nbr, const int* __restrict__ edst,
    const float* __restrict__ dt, const float* __restrict__ ef,
    const float* __restrict__ time_w, const float* __restrict__ time_b,
    const unsigned short* __restrict__ wkT, const unsigned short* __restrict__ wvT,
    const float* __restrict__ wk_b, const float* __restrict__ wv_b,
    const float* __restrict__ Q, float* __restrict__ den, float* __restrict__ agg,
    int ndst, int E)
{
    int tid  = threadIdx.x;
    int lane = tid & 63;
    int l15  = lane & 15;
    int lk   = lane >> 4;
    int e0   = blockIdx.x * 64 + (tid >> 6) * 16;

    // ---- A-row identity (lane's edge for the A fragment) ----
    int  ea = e0 + l15;
    bool va = ea < E;
    int  na = va ? nbr[ea] : 0;
    float da = va ? dt[ea] : 0.f;
    const float* hrow = h + (size_t)(ndst + na) * 128;
    const float* erow = ef + (size_t)ea * 64;

    // ---- D-row identities (lane's 4 output edge rows) ----
    int  dstr[4];
    bool evv[4];
    #pragma unroll
    for (int j = 0; j < 4; ++j) {
        int ed = e0 + lk * 4 + j;
        evv[j]  = ed < E;
        dstr[j] = evv[j] ? edst[ed] : 0;
    }

    // ---- A fragments: a[kk] = cols [kk*32+lk*8, +8) of edge row ea ----
    frag_u a[8];
    #pragma unroll
    for (int kk = 0; kk < 8; ++kk) {
        int c0 = kk * 32 + lk * 8;
        if (kk < 4) {                               // h region (cols 0..127)
            float4 x = va ? *reinterpret_cast<const float4*>(hrow + c0)
                          : make_float4(0.f,0.f,0.f,0.f);
            float4 y = va ? *reinterpret_cast<const float4*>(hrow + c0 + 4)
                          : make_float4(0.f,0.f,0.f,0.f);
            a[kk].u[0] = pk2(x.x, x.y); a[kk].u[1] = pk2(x.z, x.w);
            a[kk].u[2] = pk2(y.x, y.y); a[kk].u[3] = pk2(y.z, y.w);
        } else if (kk < 6) {                        // ef region (cols 128..191)
            int c = c0 - 128;
            float4 x = va ? *reinterpret_cast<const float4*>(erow + c)
                          : make_float4(0.f,0.f,0.f,0.f);
            float4 y = va ? *reinterpret_cast<const float4*>(erow + c + 4)
                          : make_float4(0.f,0.f,0.f,0.f);
            a[kk].u[0] = pk2(x.x, x.y); a[kk].u[1] = pk2(x.z, x.w);
            a[kk].u[2] = pk2(y.x, y.y); a[kk].u[3] = pk2(y.z, y.w);
        } else {                                    // time region (cols 192..255)
            int j0 = c0 - 192;
            float v[8];
            #pragma unroll
            for (int t = 0; t < 8; ++t)
                v[t] = __cosf(fmaf(da, time_w[j0 + t], time_b[j0 + t]));
            a[kk].u[0] = pk2(v[0], v[1]); a[kk].u[1] = pk2(v[2], v[3]);
            a[kk].u[2] = pk2(v[4], v[5]); a[kk].u[3] = pk2(v[6], v[7]);
        }
    }

    // ---- Q gather (f32): qg[nt][j] = Q[dstr[j], nt*16 + l15] ----
    float qg[8][4];
    #pragma unroll
    for (int nt = 0; nt < 8; ++nt) {
        int gc = nt * 16 + l15;
        #pragma unroll
        for (int j = 0; j < 4; ++j)
            qg[nt][j] = Q[(size_t)dstr[j] * 128 + gc];
    }

    // ---- K GEMM (kk-outer: 8 independent accumulator chains) ----
    f32x4 ck[8];
    #pragma unroll
    for (int nt = 0; nt < 8; ++nt) ck[nt] = (f32x4){0.f, 0.f, 0.f, 0.f};
    #pragma unroll
    for (int kk = 0; kk < 8; ++kk) {
        #pragma unroll
        for (int nt = 0; nt < 8; ++nt) {
            short8 b = *reinterpret_cast<const short8*>(
                wkT + (size_t)(nt * 16 + l15) * 256 + kk * 32 + lk * 8);
            ck[nt] = __builtin_amdgcn_mfma_f32_16x16x32_bf16(a[kk].s, b, ck[nt], 0, 0, 0);
        }
    }

    // ---- att = leaky_relu(Qh.Kh) per head; reduce over l15 lanes ----
    float p0[4], p1[4];
    #pragma unroll
    for (int j = 0; j < 4; ++j) { p0[j] = 0.f; p1[j] = 0.f; }
    #pragma unroll
    for (int nt = 0; nt < 8; ++nt) {
        float kb = wk_b[nt * 16 + l15];
        #pragma unroll
        for (int j = 0; j < 4; ++j) {
            float t = (ck[nt][j] + kb) * qg[nt][j];
            if (nt < 4) p0[j] += t; else p1[j] += t;
        }
    }
    #pragma unroll
    for (int m = 1; m <= 8; m <<= 1) {
        #pragma unroll
        for (int j = 0; j < 4; ++j) {
            p0[j] += __shfl_xor(p0[j], m, 64);
            p1[j] += __shfl_xor(p1[j], m, 64);
        }
    }
    float ex0[4], ex1[4];
    #pragma unroll
    for (int j = 0; j < 4; ++j) {
        float r0 = p0[j]; r0 = (r0 >= 0.f) ? r0 : 0.2f * r0;
        float r1 = p1[j]; r1 = (r1 >= 0.f) ? r1 : 0.2f * r1;
        ex0[j] = __expf(r0);
        ex1[j] = __expf(r1);
    }
    if (l15 == 0) {
        #pragma unroll
        for (int j = 0; j < 4; ++j)
            if (evv[j]) {
                atomicAdd(&den[(size_t)dstr[j] * 2 + 0], ex0[j]);
                atomicAdd(&den[(size_t)dstr[j] * 2 + 1], ex1[j]);
            }
    }

    // ---- V GEMM ----
    f32x4 cv[8];
    #pragma unroll
    for (int nt = 0; nt < 8; ++nt) cv[nt] = (f32x4){0.f, 0.f, 0.f, 0.f};
    #pragma unroll
    for (int kk = 0; kk < 8; ++kk) {
        #pragma unroll
        for (int nt = 0; nt < 8; ++nt) {
            short8 b = *reinterpret_cast<const short8*>(
                wvT + (size_t)(nt * 16 + l15) * 256 + kk * 32 + lk * 8);
            cv[nt] = __builtin_amdgcn_mfma_f32_16x16x32_bf16(a[kk].s, b, cv[nt], 0, 0, 0);
        }
    }

    // ---- weighted scatter: agg[dst, c] += ex * (V + vb) ----
    #pragma unroll
    for (int nt = 0; nt < 8; ++nt) {
        int gc = nt * 16 + l15;
        float vb = wv_b[gc];
        #pragma unroll
        for (int j = 0; j < 4; ++j)
            if (evv[j]) {
                float s = (nt < 4) ? ex0[j] : ex1[j];
                atomicAdd(&agg[(size_t)dstr[j] * 128 + gc], (cv[nt][j] + vb) * s);
            }
    }
}

// out = LN(relu([agg/den, h_dst] @ wo + wo_b)) * g + b   (f32 out)
__global__ __launch_bounds__(256) void k_out(
    const float* __restrict__ agg, const float* __restrict__ den,
    const float* __restrict__ h, const float* __restrict__ wo_w, const float* __restrict__ wo_b,
    const float* __restrict__ ln_g, const float* __restrict__ ln_b,
    float* __restrict__ out, int ndst)
{
    __shared__ float As[64 * 256];  // 64 KB
    int row0 = blockIdx.x * 64;
    int tid = threadIdx.x;
    for (int idx = tid; idx < 64 * 256; idx += 256) {
        int r = idx >> 8, c = idx & 255;
        int gr = row0 + r;
        float v = 0.f;
        if (gr < ndst) {
            if (c < 128) {
                float dd = den[(size_t)gr * 2 + (c >> 6)];
                v = (dd > 0.f) ? agg[(size_t)gr * 128 + c] / dd : 0.f;
            } else {
                v = h[(size_t)gr * 128 + (c - 128)];
            }
        }
        As[idx] = v;
    }
    __syncthreads();
    int cg = tid & 31, rg = tid >> 5;
    int c0 = cg * 4;
    float acc[8][4];
    #pragma unroll
    for (int i = 0; i < 8; ++i) { acc[i][0]=0.f; acc[i][1]=0.f; acc[i][2]=0.f; acc[i][3]=0.f; }
    for (int k = 0; k < 256; k += 4) {
        float4 w0 = *reinterpret_cast<const float4*>(wo_w + (size_t)(k+0)*128 + c0);
        float4 w1 = *reinterpret_cast<const float4*>(wo_w + (size_t)(k+1)*128 + c0);
        float4 w2 = *reinterpret_cast<const float4*>(wo_w + (size_t)(k+2)*128 + c0);
        float4 w3 = *reinterpret_cast<const float4*>(wo_w + (size_t)(k+3)*128 + c0);
        #pragma unroll
        for (int i = 0; i < 8; ++i) {
            float4 a = *reinterpret_cast<const float4*>(&As[(rg*8+i)*256 + k]);
            acc[i][0] = fmaf(a.x,w0.x,fmaf(a.y,w1.x,fmaf(a.z,w2.x,fmaf(a.w,w3.x,acc[i][0]))));
            acc[i][1] = fmaf(a.x,w0.y,fmaf(a.y,w1.y,fmaf(a.z,w2.y,fmaf(a.w,w3.y,acc[i][1]))));
            acc[i][2] = fmaf(a.x,w0.z,fmaf(a.y,w1.z,fmaf(a.z,w2.z,fmaf(a.w,w3.z,acc[i][2]))));
            acc[i][3] = fmaf(a.x,w0.w,fmaf(a.y,w1.w,fmaf(a.z,w2.w,fmaf(a.w,w3.w,acc[i][3]))));
        }
    }
    float b0 = wo_b[c0], b1 = wo_b[c0+1], b2 = wo_b[c0+2], b3 = wo_b[c0+3];
    float g0 = ln_g[c0], g1 = ln_g[c0+1], g2 = ln_g[c0+2], g3 = ln_g[c0+3];
    float l0 = ln_b[c0], l1 = ln_b[c0+1], l2 = ln_b[c0+2], l3 = ln_b[c0+3];
    #pragma unroll
    for (int i = 0; i < 8; ++i) {
        float x0 = fmaxf(acc[i][0] + b0, 0.f);
        float x1 = fmaxf(acc[i][1] + b1, 0.f);
        float x2 = fmaxf(acc[i][2] + b2, 0.f);
        float x3 = fmaxf(acc[i][3] + b3, 0.f);
        float s1 = x0 + x1 + x2 + x3;
        float s2 = x0*x0 + x1*x1 + x2*x2 + x3*x3;
        #pragma unroll
        for (int mm = 1; mm <= 16; mm <<= 1) {
            s1 += __shfl_xor(s1, mm, 64);
            s2 += __shfl_xor(s2, mm, 64);
        }
        float mean = s1 * (1.f / 128.f);
        float var  = s2 * (1.f / 128.f) - mean * mean;
        float rstd = rsqrtf(var + 1e-5f);
        int r = row0 + rg * 8 + i;
        if (r < ndst) {
            float4 o = make_float4((x0 - mean) * rstd * g0 + l0,
                                   (x1 - mean) * rstd * g1 + l1,
                                   (x2 - mean) * rstd * g2 + l2,
                                   (x3 - mean) * rstd * g3 + l3);
            *reinterpret_cast<float4*>(out + (size_t)r * 128 + c0) = o;
        }
    }
}

extern "C" void kernel_launch(void* const* d_in, const int* in_sizes, int n_in,
                              void* d_out, int out_size, void* d_ws, size_t ws_size,
                              hipStream_t stream) {
    const float* h      = (const float*)d_in[0];
    const float* dt     = (const float*)d_in[1];
    const float* ef     = (const float*)d_in[2];
    const float* time_w = (const float*)d_in[3];
    const float* time_b = (const float*)d_in[4];
    const float* wq_w   = (const float*)d_in[5];
    const float* wq_b   = (const float*)d_in[6];
    const float* wk_w   = (const float*)d_in[7];
    const float* wk_b   = (const float*)d_in[8];
    const float* wv_w   = (const float*)d_in[9];
    const float* wv_b   = (const float*)d_in[10];
    const float* wo_w   = (const float*)d_in[11];
    const float* wo_b   = (const float*)d_in[12];
    const float* ln_g   = (const float*)d_in[13];
    const float* ln_b   = (const float*)d_in[14];
    const int* nbr      = (const int*)d_in[15];
    const int* edst     = (const int*)d_in[16];

    int E    = in_sizes[1];
    int ndst = out_size / 128;

    float* ws    = (float*)d_ws;
    float* qbias = ws;                          // 128
    float* den   = qbias + 128;                 // 2*ndst
    float* Q     = den + (size_t)ndst * 2;      // ndst*128
    float* agg   = Q + (size_t)ndst * 128;      // ndst*128
    unsigned short* wkT = (unsigned short*)(agg + (size_t)ndst * 128);  // 128*256 bf16
    unsigned short* wvT = wkT + 128 * 256;
    // total ~51.7 MB

    k_init<<<2048, 256, 0, stream>>>(agg, den, ndst);
    k_prep<<<1, 128, 0, stream>>>(qbias, wq_w, wq_b, time_b);
    k_pack<<<128, 256, 0, stream>>>(wkT, wvT, wk_w, wv_w);
    k_q<<<(ndst + 63) / 64, 256, 0, stream>>>(Q, h, wq_w, qbias, ndst);
    k_kv<<<(E + 63) / 64, 256, 0, stream>>>(h, nbr, edst, dt, ef, time_w, time_b,
                                            wkT, wvT, wk_b, wv_b, Q, den, agg, ndst, E);
    k_out<<<(ndst + 63) / 64, 256, 0, stream>>>(agg, den, h, wo_w, wo_b, ln_g, ln_b,
                                                (float*)d_out, ndst);
}